// Round 2
// baseline (478.525 us; speedup 1.0000x reference)
//
#include <hip/hip_runtime.h>

// ---- problem constants (from reference) ----
#define TSTEPS 256
#define NPOP 4
#define NI 8
#define NR 8
#define NO 4
#define NF 28            // NI + 2*NR + NO
#define RANDN 512
#define NBATCH 64
#define NSTATES (NPOP*RANDN)   // 2048
#define THREADS 512
#define SPT 4                  // states per thread
#define ALPHA 0.2f             // DT/TAU
#define ONEMA 0.8f

__device__ __forceinline__ float vexp2(float x) { return __builtin_amdgcn_exp2f(x); }
__device__ __forceinline__ float vrcp(float x)  { return __builtin_amdgcn_rcpf(x); }

// tanh(x) = 1 - 2/(e^{2x}+1), e^{2x} = 2^{x*2*log2(e)}
__device__ __forceinline__ float ftanh(float x) {
    float t = vexp2(x * 2.885390081777927f);
    return __builtin_fmaf(-2.0f, vrcp(t + 1.0f), 1.0f);
}

template<int CTRL, int RM, int BM>
__device__ __forceinline__ float dpp_add(float x) {
    int v = __builtin_amdgcn_update_dpp(0, __float_as_int(x), CTRL, RM, BM, true);
    return x + __int_as_float(v);
}

// full wave64 sum -> result valid in lane 63 (LLVM atomic-optimizer sequence)
__device__ __forceinline__ float wave_red_sum(float x) {
    x = dpp_add<0x111, 0xf, 0xf>(x);  // row_shr:1
    x = dpp_add<0x112, 0xf, 0xf>(x);  // row_shr:2
    x = dpp_add<0x114, 0xf, 0xf>(x);  // row_shr:4
    x = dpp_add<0x118, 0xf, 0xf>(x);  // row_shr:8
    x = dpp_add<0x142, 0xa, 0xf>(x);  // row_bcast:15 -> rows 1,3
    x = dpp_add<0x143, 0xc, 0xf>(x);  // row_bcast:31 -> rows 2,3
    return x;
}

// barrier with LDS-only ordering: do NOT drain vmcnt (keeps the HBM noise
// prefetch in flight across the barrier). All in-loop cross-thread data is LDS.
__device__ __forceinline__ void lds_barrier() {
    asm volatile("s_waitcnt lgkmcnt(0)\n\ts_barrier" ::: "memory");
}

__device__ __forceinline__ float4 add4(float4 a, float4 b) {
    return float4{a.x + b.x, a.y + b.y, a.z + b.z, a.w + b.w};
}

__global__ __launch_bounds__(THREADS, 1) void rnn_fused(
    const float* __restrict__ u,      // [B][T][NI]
    const float* __restrict__ G,      // [NPOP]
    const float* __restrict__ mu,     // [NPOP][NF]
    const float* __restrict__ C,      // [NPOP][NF][NF]
    const float* __restrict__ h0,     // [NPOP][RANDN]
    const float* __restrict__ nl,     // [NPOP][RANDN][NF]
    const float* __restrict__ nrec,   // [B][T][NPOP][RANDN]
    float* __restrict__ y)            // [B][T+1][NO]
{
    __shared__ float u_lds[TSTEPS * NI];                 // 8 KB
    __shared__ float c_lds[NPOP * NF * NF];              // 12.25 KB
    __shared__ float mu_lds[NPOP * NF];
    __shared__ __align__(16) float wredK[2][8][8];       // double-buffered kappa partials
    __shared__ __align__(16) float ybuf[TSTEPS + 1][8][4]; // deferred y partials, 32.9 KB

    const int tid  = threadIdx.x;
    const int b    = blockIdx.x;
    const int lane = tid & 63;
    const int wid  = tid >> 6;
    const int p    = tid >> 7;          // 128 threads per population
    const int s0   = tid * SPT;         // first global state index

    // ---- stage u[b] into LDS (2048 floats) ----
    {
        const float4* src = (const float4*)(u + (size_t)b * TSTEPS * NI);
        ((float4*)u_lds)[tid] = src[tid];
    }
    // ---- stage C into LDS (784 float4) ----
    {
        const float4* src = (const float4*)C;
        float4* dst = (float4*)c_lds;
        #pragma unroll
        for (int i = 0; i < 2; ++i) {
            int idx = tid + i * THREADS;
            if (idx < NPOP * NF * NF / 4) dst[idx] = src[idx];
        }
    }
    if (tid < NPOP * NF) mu_lds[tid] = mu[tid];

    // ---- softmax(G)/RANDN for this thread's population ----
    float w_p;
    {
        float g0 = G[0], g1 = G[1], g2 = G[2], g3 = G[3];
        float m = fmaxf(fmaxf(g0, g1), fmaxf(g2, g3));
        const float L2E = 1.4426950408889634f;
        float e0 = vexp2((g0 - m) * L2E), e1 = vexp2((g1 - m) * L2E);
        float e2 = vexp2((g2 - m) * L2E), e3 = vexp2((g3 - m) * L2E);
        float inv = vrcp(e0 + e1 + e2 + e3);
        float ap = (p == 0) ? e0 : (p == 1) ? e1 : (p == 2) ? e2 : e3;
        w_p = ap * inv * (1.0f / (float)RANDN);
    }
    __syncthreads();

    // ---- compute loading rows for this thread's 4 states ----
    // W[k][f]: f in [0,8)=alpha*I, [8,16)=alpha*U, [16,24)=w*V, [24,28)=w*O
    float W[SPT][NF];
    #pragma unroll
    for (int f = 0; f < NF; ++f) {
        float m = mu_lds[p * NF + f];
        W[0][f] = m; W[1][f] = m; W[2][f] = m; W[3][f] = m;
    }
    #pragma unroll
    for (int pr = 0; pr < 2; ++pr) {        // 2 states at a time (register pressure)
        float nlr[2][NF];
        #pragma unroll
        for (int kk = 0; kk < 2; ++kk) {
            const float4* src = (const float4*)(nl + (size_t)(s0 + pr * 2 + kk) * NF);
            #pragma unroll
            for (int q = 0; q < 7; ++q) {
                float4 v = src[q];
                nlr[kk][q*4+0] = v.x; nlr[kk][q*4+1] = v.y;
                nlr[kk][q*4+2] = v.z; nlr[kk][q*4+3] = v.w;
            }
        }
        #pragma unroll
        for (int f = 0; f < NF; ++f) {
            const float4* cr = (const float4*)&c_lds[(p * NF + f) * NF];
            float crow[NF];
            #pragma unroll
            for (int q = 0; q < 7; ++q) {
                float4 v = cr[q];
                crow[q*4+0] = v.x; crow[q*4+1] = v.y;
                crow[q*4+2] = v.z; crow[q*4+3] = v.w;
            }
            #pragma unroll
            for (int kk = 0; kk < 2; ++kk) {
                float acc = W[pr*2+kk][f];
                #pragma unroll
                for (int ss = 0; ss < NF; ++ss)
                    acc = __builtin_fmaf(crow[ss], nlr[kk][ss], acc);
                W[pr*2+kk][f] = acc;
            }
        }
    }
    // scale: I,U by alpha; V,O by w_p
    #pragma unroll
    for (int k = 0; k < SPT; ++k) {
        #pragma unroll
        for (int f = 0; f < 16; ++f) W[k][f] *= ALPHA;
        #pragma unroll
        for (int f = 16; f < NF; ++f) W[k][f] *= w_p;
    }

    // ---- init h, noise prefetch, output base ----
    float h[SPT];
    {
        float4 v = *(const float4*)(h0 + s0);
        h[0] = v.x; h[1] = v.y; h[2] = v.z; h[3] = v.w;
    }
    const float4* npf = (const float4*)nrec + (size_t)b * (TSTEPS * NSTATES / 4) + tid;
    float4 ncur = npf[0];
    float* yout = y + (size_t)b * (TSTEPS + 1) * NO;

    // ---- main sequential loop: ONE barrier per step, vmcnt never drained ----
    for (int t = 0; t < TSTEPS; ++t) {
        int tn = (t + 1 < TSTEPS) ? (t + 1) : t;
        float4 nnext = npf[(size_t)tn * (NSTATES / 4)];   // stays in flight across barrier

        // phi = tanh(h_t); partials: kappa[8] (wV), y[4] (wO)
        float red[12];
        {
            float phi0 = ftanh(h[0]), phi1 = ftanh(h[1]);
            float phi2 = ftanh(h[2]), phi3 = ftanh(h[3]);
            #pragma unroll
            for (int r = 0; r < 8; ++r)
                red[r] = __builtin_fmaf(phi0, W[0][16+r],
                         __builtin_fmaf(phi1, W[1][16+r],
                         __builtin_fmaf(phi2, W[2][16+r], phi3 * W[3][16+r])));
            #pragma unroll
            for (int o = 0; o < 4; ++o)
                red[8+o] = __builtin_fmaf(phi0, W[0][24+o],
                           __builtin_fmaf(phi1, W[1][24+o],
                           __builtin_fmaf(phi2, W[2][24+o], phi3 * W[3][24+o])));
        }
        #pragma unroll
        for (int i = 0; i < 12; ++i) red[i] = wave_red_sum(red[i]);

        if (lane == 63) {
            *(float4*)&wredK[t & 1][wid][0] = float4{red[0], red[1], red[2],  red[3]};
            *(float4*)&wredK[t & 1][wid][4] = float4{red[4], red[5], red[6],  red[7]};
            *(float4*)&ybuf[t][wid][0]      = float4{red[8], red[9], red[10], red[11]};
        }
        lds_barrier();

        // every thread: direct 8-wave sum of kappa partials (broadcast reads)
        float4 k03, k47;
        {
            const float* wb = &wredK[t & 1][0][0];
            float4 a0 = *(const float4*)(wb +  0), b0 = *(const float4*)(wb +  4);
            float4 a1 = *(const float4*)(wb +  8), b1 = *(const float4*)(wb + 12);
            float4 a2 = *(const float4*)(wb + 16), b2 = *(const float4*)(wb + 20);
            float4 a3 = *(const float4*)(wb + 24), b3 = *(const float4*)(wb + 28);
            float4 a4 = *(const float4*)(wb + 32), b4 = *(const float4*)(wb + 36);
            float4 a5 = *(const float4*)(wb + 40), b5 = *(const float4*)(wb + 44);
            float4 a6 = *(const float4*)(wb + 48), b6 = *(const float4*)(wb + 52);
            float4 a7 = *(const float4*)(wb + 56), b7 = *(const float4*)(wb + 60);
            k03 = add4(add4(add4(a0, a1), add4(a2, a3)), add4(add4(a4, a5), add4(a6, a7)));
            k47 = add4(add4(add4(b0, b1), add4(b2, b3)), add4(add4(b4, b5), add4(b6, b7)));
        }
        float kf[8] = {k03.x, k03.y, k03.z, k03.w, k47.x, k47.y, k47.z, k47.w};

        float ut[8];
        {
            const float4* up = (const float4*)&u_lds[t * NI];
            float4 a = up[0], bb = up[1];
            ut[0]=a.x; ut[1]=a.y; ut[2]=a.z; ut[3]=a.w;
            ut[4]=bb.x; ut[5]=bb.y; ut[6]=bb.z; ut[7]=bb.w;
        }
        float nn[4] = {ncur.x, ncur.y, ncur.z, ncur.w};
        #pragma unroll
        for (int k = 0; k < SPT; ++k) {
            float acc0 = ALPHA * nn[k];
            acc0 = __builtin_fmaf(kf[0], W[k][8],  acc0);
            acc0 = __builtin_fmaf(kf[1], W[k][9],  acc0);
            acc0 = __builtin_fmaf(kf[2], W[k][10], acc0);
            acc0 = __builtin_fmaf(kf[3], W[k][11], acc0);
            acc0 = __builtin_fmaf(ut[0], W[k][0],  acc0);
            acc0 = __builtin_fmaf(ut[1], W[k][1],  acc0);
            acc0 = __builtin_fmaf(ut[2], W[k][2],  acc0);
            acc0 = __builtin_fmaf(ut[3], W[k][3],  acc0);
            float acc1 = kf[4] * W[k][12];
            acc1 = __builtin_fmaf(kf[5], W[k][13], acc1);
            acc1 = __builtin_fmaf(kf[6], W[k][14], acc1);
            acc1 = __builtin_fmaf(kf[7], W[k][15], acc1);
            acc1 = __builtin_fmaf(ut[4], W[k][4],  acc1);
            acc1 = __builtin_fmaf(ut[5], W[k][5],  acc1);
            acc1 = __builtin_fmaf(ut[6], W[k][6],  acc1);
            acc1 = __builtin_fmaf(ut[7], W[k][7],  acc1);
            h[k] = __builtin_fmaf(ONEMA, h[k], acc0 + acc1);
        }
        ncur = nnext;
    }

    // ---- final output row partials y[b, T, :] from h_T ----
    {
        float phi0 = ftanh(h[0]), phi1 = ftanh(h[1]);
        float phi2 = ftanh(h[2]), phi3 = ftanh(h[3]);
        float red[4];
        #pragma unroll
        for (int o = 0; o < 4; ++o)
            red[o] = __builtin_fmaf(phi0, W[0][24+o],
                     __builtin_fmaf(phi1, W[1][24+o],
                     __builtin_fmaf(phi2, W[2][24+o], phi3 * W[3][24+o])));
        #pragma unroll
        for (int o = 0; o < 4; ++o) red[o] = wave_red_sum(red[o]);
        if (lane == 63)
            *(float4*)&ybuf[TSTEPS][wid][0] = float4{red[0], red[1], red[2], red[3]};
    }
    lds_barrier();

    // ---- deferred y reduction: 1028 outputs, each sum of 8 wave partials ----
    for (int idx = tid; idx < (TSTEPS + 1) * NO; idx += THREADS) {
        int t = idx >> 2, o = idx & 3;
        float s = ((ybuf[t][0][o] + ybuf[t][1][o]) + (ybuf[t][2][o] + ybuf[t][3][o]))
                + ((ybuf[t][4][o] + ybuf[t][5][o]) + (ybuf[t][6][o] + ybuf[t][7][o]));
        yout[idx] = s;
    }
}

extern "C" void kernel_launch(void* const* d_in, const int* in_sizes, int n_in,
                              void* d_out, int out_size, void* d_ws, size_t ws_size,
                              hipStream_t stream) {
    const float* u    = (const float*)d_in[0];
    const float* G    = (const float*)d_in[1];
    const float* mu   = (const float*)d_in[2];
    const float* C    = (const float*)d_in[3];
    const float* h0   = (const float*)d_in[4];
    const float* nl   = (const float*)d_in[5];
    const float* nrec = (const float*)d_in[6];
    float* y = (float*)d_out;

    rnn_fused<<<dim3(NBATCH), dim3(THREADS), 0, stream>>>(u, G, mu, C, h0, nl, nrec, y);
}

// Round 3
// 337.889 us; speedup vs baseline: 1.4162x; 1.4162x over previous
//
#include <hip/hip_runtime.h>

// ---- problem constants (from reference) ----
#define TSTEPS 256
#define NPOP 4
#define NI 8
#define NR 8
#define NO 4
#define NF 28            // NI + 2*NR + NO
#define RANDN 512
#define NBATCH 64
#define NSTATES (NPOP*RANDN)   // 2048
#define THREADS 512
#define SPT 4                  // states per thread
#define ALPHA 0.2f             // DT/TAU
#define ONEMA 0.8f

__device__ __forceinline__ float vexp2(float x) { return __builtin_amdgcn_exp2f(x); }
__device__ __forceinline__ float vrcp(float x)  { return __builtin_amdgcn_rcpf(x); }

// tanh(x) = 1 - 2/(e^{2x}+1), e^{2x} = 2^{x*2*log2(e)}
__device__ __forceinline__ float ftanh(float x) {
    float t = vexp2(x * 2.885390081777927f);
    return __builtin_fmaf(-2.0f, vrcp(t + 1.0f), 1.0f);
}

template<int CTRL, int RM, int BM>
__device__ __forceinline__ float dpp_add(float x) {
    int v = __builtin_amdgcn_update_dpp(0, __float_as_int(x), CTRL, RM, BM, true);
    return x + __int_as_float(v);
}

// full wave64 sum -> result valid in lane 63
__device__ __forceinline__ float wave_red_sum(float x) {
    x = dpp_add<0x111, 0xf, 0xf>(x);  // row_shr:1
    x = dpp_add<0x112, 0xf, 0xf>(x);  // row_shr:2
    x = dpp_add<0x114, 0xf, 0xf>(x);  // row_shr:4
    x = dpp_add<0x118, 0xf, 0xf>(x);  // row_shr:8
    x = dpp_add<0x142, 0xa, 0xf>(x);  // row_bcast:15 -> rows 1,3
    x = dpp_add<0x143, 0xc, 0xf>(x);  // row_bcast:31 -> rows 2,3
    return x;
}

// barrier with LDS-only ordering: do NOT drain vmcnt (keeps the HBM noise
// prefetch in flight across the barrier). All in-loop cross-thread data is LDS.
__device__ __forceinline__ void lds_barrier() {
    asm volatile("s_waitcnt lgkmcnt(0)\n\ts_barrier" ::: "memory");
}

__device__ __forceinline__ float readlane_f(float x, int l) {
    return __uint_as_float(__builtin_amdgcn_readlane(__float_as_uint(x), l));
}

__global__ __launch_bounds__(THREADS, 2) void rnn_fused(
    const float* __restrict__ u,      // [B][T][NI]
    const float* __restrict__ G,      // [NPOP]
    const float* __restrict__ mu,     // [NPOP][NF]
    const float* __restrict__ C,      // [NPOP][NF][NF]
    const float* __restrict__ h0,     // [NPOP][RANDN]
    const float* __restrict__ nl,     // [NPOP][RANDN][NF]
    const float* __restrict__ nrec,   // [B][T][NPOP][RANDN]
    float* __restrict__ y)            // [B][T+1][NO]
{
    __shared__ float u_lds[TSTEPS * NI];                   // 8 KB
    __shared__ float c_lds[NPOP * NF * NF];                // 12.25 KB
    __shared__ float mu_lds[NPOP * NF];
    __shared__ __align__(16) float part[2][8][8];          // kappa partials, dbuf
    __shared__ __align__(16) float ybuf[TSTEPS + 1][8][4]; // deferred y partials

    const int tid  = threadIdx.x;
    const int b    = blockIdx.x;
    const int lane = tid & 63;
    const int wid  = tid >> 6;
    const int p    = tid >> 7;          // 128 threads per population
    const int s0   = tid * SPT;         // first global state index

    // ---- stage u[b] into LDS (2048 floats) ----
    {
        const float4* src = (const float4*)(u + (size_t)b * TSTEPS * NI);
        ((float4*)u_lds)[tid] = src[tid];
    }
    // ---- stage C into LDS (784 float4) ----
    {
        const float4* src = (const float4*)C;
        float4* dst = (float4*)c_lds;
        #pragma unroll
        for (int i = 0; i < 2; ++i) {
            int idx = tid + i * THREADS;
            if (idx < NPOP * NF * NF / 4) dst[idx] = src[idx];
        }
    }
    if (tid < NPOP * NF) mu_lds[tid] = mu[tid];

    // ---- softmax(G)/RANDN for this thread's population ----
    float w_p;
    {
        float g0 = G[0], g1 = G[1], g2 = G[2], g3 = G[3];
        float m = fmaxf(fmaxf(g0, g1), fmaxf(g2, g3));
        const float L2E = 1.4426950408889634f;
        float e0 = vexp2((g0 - m) * L2E), e1 = vexp2((g1 - m) * L2E);
        float e2 = vexp2((g2 - m) * L2E), e3 = vexp2((g3 - m) * L2E);
        float inv = vrcp(e0 + e1 + e2 + e3);
        float ap = (p == 0) ? e0 : (p == 1) ? e1 : (p == 2) ? e2 : e3;
        w_p = ap * inv * (1.0f / (float)RANDN);
    }
    __syncthreads();

    // ---- compute loading rows for this thread's 4 states ----
    // W[k][f]: f in [0,8)=alpha*I, [8,16)=alpha*U, [16,24)=w*V, [24,28)=w*O
    float W[SPT][NF];
    #pragma unroll
    for (int f = 0; f < NF; ++f) {
        float m = mu_lds[p * NF + f];
        W[0][f] = m; W[1][f] = m; W[2][f] = m; W[3][f] = m;
    }
    #pragma unroll
    for (int pr = 0; pr < 2; ++pr) {        // 2 states at a time (register pressure)
        float nlr[2][NF];
        #pragma unroll
        for (int kk = 0; kk < 2; ++kk) {
            const float4* src = (const float4*)(nl + (size_t)(s0 + pr * 2 + kk) * NF);
            #pragma unroll
            for (int q = 0; q < 7; ++q) {
                float4 v = src[q];
                nlr[kk][q*4+0] = v.x; nlr[kk][q*4+1] = v.y;
                nlr[kk][q*4+2] = v.z; nlr[kk][q*4+3] = v.w;
            }
        }
        #pragma unroll
        for (int f = 0; f < NF; ++f) {
            const float4* cr = (const float4*)&c_lds[(p * NF + f) * NF];
            float crow[NF];
            #pragma unroll
            for (int q = 0; q < 7; ++q) {
                float4 v = cr[q];
                crow[q*4+0] = v.x; crow[q*4+1] = v.y;
                crow[q*4+2] = v.z; crow[q*4+3] = v.w;
            }
            #pragma unroll
            for (int kk = 0; kk < 2; ++kk) {
                float acc = W[pr*2+kk][f];
                #pragma unroll
                for (int ss = 0; ss < NF; ++ss)
                    acc = __builtin_fmaf(crow[ss], nlr[kk][ss], acc);
                W[pr*2+kk][f] = acc;
            }
        }
    }
    // scale: I,U by alpha; V,O by w_p
    #pragma unroll
    for (int k = 0; k < SPT; ++k) {
        #pragma unroll
        for (int f = 0; f < 16; ++f) W[k][f] *= ALPHA;
        #pragma unroll
        for (int f = 16; f < NF; ++f) W[k][f] *= w_p;
    }

    // ---- init h, depth-2 noise prefetch, output base ----
    float h[SPT];
    {
        float4 v = *(const float4*)(h0 + s0);
        h[0] = v.x; h[1] = v.y; h[2] = v.z; h[3] = v.w;
    }
    const float4* npf = (const float4*)nrec + (size_t)b * (TSTEPS * NSTATES / 4) + tid;
    float4 nbuf0 = npf[0];
    float4 nbuf1 = npf[NSTATES / 4];
    float* yout = y + (size_t)b * (TSTEPS + 1) * NO;

    // ---- main sequential loop: ONE barrier per step, vmcnt never drained ----
    #pragma unroll 2
    for (int t = 0; t < TSTEPS; ++t) {
        // use nbuf0 this step; prefetch t+2 into its slot (static with unroll 2)
        float4 nn4 = nbuf0;
        int tp = (t + 2 < TSTEPS) ? (t + 2) : (TSTEPS - 1);
        nbuf0 = nbuf1;
        nbuf1 = npf[(size_t)tp * (NSTATES / 4)];

        // phi = tanh(h_t); partials: kappa[8] (wV), y[4] (wO)
        float red[12];
        {
            float phi0 = ftanh(h[0]), phi1 = ftanh(h[1]);
            float phi2 = ftanh(h[2]), phi3 = ftanh(h[3]);
            #pragma unroll
            for (int r = 0; r < 8; ++r)
                red[r] = __builtin_fmaf(phi0, W[0][16+r],
                         __builtin_fmaf(phi1, W[1][16+r],
                         __builtin_fmaf(phi2, W[2][16+r], phi3 * W[3][16+r])));
            #pragma unroll
            for (int o = 0; o < 4; ++o)
                red[8+o] = __builtin_fmaf(phi0, W[0][24+o],
                           __builtin_fmaf(phi1, W[1][24+o],
                           __builtin_fmaf(phi2, W[2][24+o], phi3 * W[3][24+o])));
        }
        #pragma unroll
        for (int i = 0; i < 12; ++i) red[i] = wave_red_sum(red[i]);

        if (lane == 63) {
            *(float4*)&part[t & 1][wid][0] = float4{red[0], red[1], red[2],  red[3]};
            *(float4*)&part[t & 1][wid][4] = float4{red[4], red[5], red[6],  red[7]};
            *(float4*)&ybuf[t][wid][0]     = float4{red[8], red[9], red[10], red[11]};
        }
        lds_barrier();

        // stage 2: 1 LDS read + xor-butterfly over the 8 waves + readlane -> SGPRs
        float pv = ((const float*)&part[t & 1][0][0])[lane];  // wave=lane>>3, val=lane&7
        pv += __shfl_xor(pv, 8,  64);
        pv += __shfl_xor(pv, 16, 64);
        pv += __shfl_xor(pv, 32, 64);
        float kf0 = readlane_f(pv, 0), kf1 = readlane_f(pv, 1);
        float kf2 = readlane_f(pv, 2), kf3 = readlane_f(pv, 3);
        float kf4 = readlane_f(pv, 4), kf5 = readlane_f(pv, 5);
        float kf6 = readlane_f(pv, 6), kf7 = readlane_f(pv, 7);

        float ut[8];
        {
            const float4* up = (const float4*)&u_lds[t * NI];
            float4 a = up[0], bb = up[1];
            ut[0]=a.x; ut[1]=a.y; ut[2]=a.z; ut[3]=a.w;
            ut[4]=bb.x; ut[5]=bb.y; ut[6]=bb.z; ut[7]=bb.w;
        }
        float nn[4] = {nn4.x, nn4.y, nn4.z, nn4.w};
        #pragma unroll
        for (int k = 0; k < SPT; ++k) {
            float acc0 = ALPHA * nn[k];
            acc0 = __builtin_fmaf(kf0, W[k][8],  acc0);
            acc0 = __builtin_fmaf(kf1, W[k][9],  acc0);
            acc0 = __builtin_fmaf(kf2, W[k][10], acc0);
            acc0 = __builtin_fmaf(kf3, W[k][11], acc0);
            acc0 = __builtin_fmaf(ut[0], W[k][0], acc0);
            acc0 = __builtin_fmaf(ut[1], W[k][1], acc0);
            acc0 = __builtin_fmaf(ut[2], W[k][2], acc0);
            acc0 = __builtin_fmaf(ut[3], W[k][3], acc0);
            float acc1 = kf4 * W[k][12];
            acc1 = __builtin_fmaf(kf5, W[k][13], acc1);
            acc1 = __builtin_fmaf(kf6, W[k][14], acc1);
            acc1 = __builtin_fmaf(kf7, W[k][15], acc1);
            acc1 = __builtin_fmaf(ut[4], W[k][4], acc1);
            acc1 = __builtin_fmaf(ut[5], W[k][5], acc1);
            acc1 = __builtin_fmaf(ut[6], W[k][6], acc1);
            acc1 = __builtin_fmaf(ut[7], W[k][7], acc1);
            h[k] = __builtin_fmaf(ONEMA, h[k], acc0 + acc1);
        }
    }

    // ---- final output row partials y[b, T, :] from h_T ----
    {
        float phi0 = ftanh(h[0]), phi1 = ftanh(h[1]);
        float phi2 = ftanh(h[2]), phi3 = ftanh(h[3]);
        float red[4];
        #pragma unroll
        for (int o = 0; o < 4; ++o)
            red[o] = __builtin_fmaf(phi0, W[0][24+o],
                     __builtin_fmaf(phi1, W[1][24+o],
                     __builtin_fmaf(phi2, W[2][24+o], phi3 * W[3][24+o])));
        #pragma unroll
        for (int o = 0; o < 4; ++o) red[o] = wave_red_sum(red[o]);
        if (lane == 63)
            *(float4*)&ybuf[TSTEPS][wid][0] = float4{red[0], red[1], red[2], red[3]};
    }
    lds_barrier();

    // ---- deferred y reduction: 1028 outputs, each sum of 8 wave partials ----
    for (int idx = tid; idx < (TSTEPS + 1) * NO; idx += THREADS) {
        int t = idx >> 2, o = idx & 3;
        float s = ((ybuf[t][0][o] + ybuf[t][1][o]) + (ybuf[t][2][o] + ybuf[t][3][o]))
                + ((ybuf[t][4][o] + ybuf[t][5][o]) + (ybuf[t][6][o] + ybuf[t][7][o]));
        yout[idx] = s;
    }
}

extern "C" void kernel_launch(void* const* d_in, const int* in_sizes, int n_in,
                              void* d_out, int out_size, void* d_ws, size_t ws_size,
                              hipStream_t stream) {
    const float* u    = (const float*)d_in[0];
    const float* G    = (const float*)d_in[1];
    const float* mu   = (const float*)d_in[2];
    const float* C    = (const float*)d_in[3];
    const float* h0   = (const float*)d_in[4];
    const float* nl   = (const float*)d_in[5];
    const float* nrec = (const float*)d_in[6];
    float* y = (float*)d_out;

    rnn_fused<<<dim3(NBATCH), dim3(THREADS), 0, stream>>>(u, G, mu, C, h0, nl, nrec, y);
}